// Round 11
// baseline (245.035 us; speedup 1.0000x reference)
//
#include <hip/hip_runtime.h>
#include <hip/hip_bf16.h>
#include <hip/hip_cooperative_groups.h>

namespace cg = cooperative_groups;

#define BB 2
#define SS 1024
#define DD 256
#define NCH 4           // k-chunks in attn
#define KCH 256         // k-chunk size

typedef __attribute__((ext_vector_type(8))) short bf16x8;
typedef __attribute__((ext_vector_type(4))) float f32x4;

__device__ __forceinline__ unsigned short f2bf(float f) {
    __hip_bfloat16 h = __float2bfloat16(f);
    return *reinterpret_cast<unsigned short*>(&h);
}
__device__ __forceinline__ float bf2f(unsigned short u) {
    __hip_bfloat16 h;
    *reinterpret_cast<unsigned short*>(&h) = u;
    return __bfloat162float(h);
}
__device__ __forceinline__ bf16x8 cvt8(float4 f0, float4 f1) {
    bf16x8 o;
    o[0] = (short)f2bf(f0.x); o[1] = (short)f2bf(f0.y);
    o[2] = (short)f2bf(f0.z); o[3] = (short)f2bf(f0.w);
    o[4] = (short)f2bf(f1.x); o[5] = (short)f2bf(f1.y);
    o[6] = (short)f2bf(f1.z); o[7] = (short)f2bf(f1.w);
    return o;
}

// ===========================================================================
// FUSED cooperative kernel: cvt -> qkv -> attn -> combine with grid.sync()
// between phases. Phase bodies are R8's kernels verbatim (bit-identical
// numerics). grid = 512 blocks x 256 thr; launch_bounds(256,2) guarantees
// 2 blocks/CU co-residency (VGPR<=256, LDS 9.4KB). Tests H_A: inter-kernel
// launch/drain bubbles vs in-kernel latency.
// ===========================================================================
__global__ __launch_bounds__(256, 2) void geo_fused(
    const float* __restrict__ x,
    const float* __restrict__ Wq, const float* __restrict__ bq,
    const float* __restrict__ Wk, const float* __restrict__ bk,
    const float* __restrict__ Wv, const float* __restrict__ bv,
    const float* __restrict__ Wo, const float* __restrict__ bo,
    float* __restrict__ out, unsigned char* __restrict__ ws)
{
    cg::grid_group grid = cg::this_grid();
    const int t = threadIdx.x;
    const int bx = blockIdx.x;
    const int w = t >> 6, l = t & 63, lr = l & 15, lc = l >> 4;

    // ws layout (matches host): Qb|Kb|VB|xb|Wqb|Wkb|Wvb|Wob||qq|kk|esum|Opart
    const size_t rows = (size_t)BB * SS;
    unsigned short* Qb  = (unsigned short*)ws;
    unsigned short* Kb  = Qb + rows * DD;
    unsigned short* VB  = Kb + rows * DD;
    unsigned short* xb  = VB + rows * DD;
    unsigned short* Wqb = xb + rows * DD;
    unsigned short* Wkb = Wqb + (size_t)DD * DD;
    unsigned short* Wvb = Wkb + (size_t)DD * DD;
    unsigned short* Wob = Wvb + (size_t)DD * DD;
    float* qq    = (float*)(Wob + (size_t)DD * DD);
    float* kk    = qq + rows;
    float* esum  = kk + rows;
    float* Opart = esum + (size_t)NCH * rows;

    // shared-memory union across phases (max = attn: 8192+1024+64+256 = 9536B)
    __shared__ __align__(16) unsigned char smem_raw[9600];

    // ---- Phase 0: fp32->bf16 conversion of x and the four weights ----
    {
        const int u = bx * 256 + t;              // unit = 8 elements
        if (u < 98304) {
            const float* src; unsigned short* dst; int base;
            if (u < 65536)      { src = x;  dst = xb;  base = u; }
            else if (u < 73728) { src = Wq; dst = Wqb; base = u - 65536; }
            else if (u < 81920) { src = Wk; dst = Wkb; base = u - 73728; }
            else if (u < 90112) { src = Wv; dst = Wvb; base = u - 81920; }
            else                { src = Wo; dst = Wob; base = u - 90112; }
            const float4* s4 = (const float4*)src + (size_t)base * 2;
            *(bf16x8*)(dst + (size_t)base * 8) = cvt8(s4[0], s4[1]);
        }
    }
    grid.sync();

    // ---- Phase 1: QKV projection (R8 body); 384 active blocks ----
    if (bx < 384) {
        float (*red)[16] = (float(*)[16])smem_raw;
        const int mat = bx % 3;
        const int tile = bx / 3;
        const int r0 = tile * 16;
        const int b = r0 >> 10;
        const int s_in_base = r0 & (SS - 1);

        const unsigned short* W = (mat == 0) ? Wqb : (mat == 1) ? Wkb : Wvb;
        const float* bias       = (mat == 0) ? bq  : (mat == 1) ? bk  : bv;

        bf16x8 af[8];
#pragma unroll
        for (int db = 0; db < 8; ++db)
            af[db] = *(const bf16x8*)(xb + (size_t)(r0 + lr) * DD + db * 32 + 8 * lc);

        float nrm[4] = {0.f, 0.f, 0.f, 0.f};

#pragma unroll
        for (int cb = 0; cb < 4; ++cb) {
            const int jb = 64 * w + 16 * cb;
            f32x4 acc = {0.f, 0.f, 0.f, 0.f};
#pragma unroll
            for (int db = 0; db < 8; ++db) {
                bf16x8 bf = *(const bf16x8*)(W + (size_t)(jb + lr) * DD + db * 32 + 8 * lc);
                acc = __builtin_amdgcn_mfma_f32_16x16x32_bf16(af[db], bf, acc, 0, 0, 0);
            }
            const float bv_ = bias[jb + lr];
#pragma unroll
            for (int r = 0; r < 4; ++r) {
                const int srow = r0 + lc * 4 + r;
                const float v = acc[r] + bv_;
                const unsigned short h = f2bf(v);
                if (mat == 0) {
                    Qb[(size_t)srow * DD + jb + lr] = h;
                    const float hv = bf2f(h); nrm[r] += hv * hv;
                } else if (mat == 1) {
                    Kb[(size_t)srow * DD + jb + lr] = h;
                    const float hv = bf2f(h); nrm[r] += hv * hv;
                } else {
                    const int s_in = s_in_base + lc * 4 + r;
                    const int kb32 = s_in >> 5;
                    const int kslot = (s_in >> 3) & 3;
                    const int jj = s_in & 7;
                    const int db16 = 4 * w + cb;
                    const size_t off = ((size_t)((b * 32 + kb32) * 16 + db16) << 9)
                                     + ((kslot * 16 + lr) << 3) + jj;
                    VB[off] = h;
                }
            }
        }

        if (mat < 2) {
#pragma unroll
            for (int r = 0; r < 4; ++r) {
                float n = nrm[r];
#pragma unroll
                for (int m = 1; m < 16; m <<= 1) n += __shfl_xor(n, m, 64);
                if (lr == 0) red[w][lc * 4 + r] = n;
            }
            __syncthreads();
            if (t < 16) {
                const float s = red[0][t] + red[1][t] + red[2][t] + red[3][t];
                if (mat == 0) qq[r0 + t] = s;
                else          kk[r0 + t] = s;
            }
        }
    }
    grid.sync();

    // ---- Phase 2: partial attention (R8 body); all 512 blocks ----
    {
        unsigned short* P_s = (unsigned short*)smem_raw;            // 8192B
        float* kk_s  = (float*)(smem_raw + 8192);                   // 1024B
        float* qq_s  = (float*)(smem_raw + 9216);                   // 64B
        float (*es_red)[16] = (float(*)[16])(smem_raw + 9280);      // 256B

        const int qtile = bx >> 2;
        const int c = bx & 3;
        const int rowbase = qtile * 16;
        const int b = rowbase >> 10;
        const int s0 = c * KCH;

        kk_s[t] = kk[b * SS + s0 + t];
        if (t < 16) qq_s[t] = qq[rowbase + t];

        bf16x8 qf[8];
#pragma unroll
        for (int db = 0; db < 8; ++db)
            qf[db] = *(const bf16x8*)(Qb + (size_t)(rowbase + lr) * DD + db * 32 + 8 * lc);

        __syncthreads();

        float psum[4] = {0.f, 0.f, 0.f, 0.f};
#pragma unroll
        for (int kbi = 0; kbi < 4; ++kbi) {
            const int kb = 64 * w + 16 * kbi;
            f32x4 acc = {0.f, 0.f, 0.f, 0.f};
#pragma unroll
            for (int db = 0; db < 8; ++db) {
                bf16x8 kf = *(const bf16x8*)(
                    Kb + (size_t)(b * SS + s0 + kb + lr) * DD + db * 32 + 8 * lc);
                acc = __builtin_amdgcn_mfma_f32_16x16x32_bf16(qf[db], kf, acc, 0, 0, 0);
            }
            const int kcol = kb + lr;
            const float kkv = kk_s[kcol];
#pragma unroll
            for (int r = 0; r < 4; ++r) {
                const int qi = lc * 4 + r;
                const float d2 = fmaxf(qq_s[qi] + kkv - 2.f * acc[r], 0.f);
                const float e = __expf(-sqrtf(d2) * 0.0625f);
                psum[r] += e;
                P_s[qi * 256 + (kcol ^ ((qi & 7) << 3))] = f2bf(e);
            }
        }
#pragma unroll
        for (int r = 0; r < 4; ++r) {
            float s = psum[r];
#pragma unroll
            for (int m = 1; m < 16; m <<= 1) s += __shfl_xor(s, m, 64);
            if (lr == 0) es_red[w][lc * 4 + r] = s;
        }
        __syncthreads();
        if (t < 16)
            esum[(size_t)c * (BB * SS) + rowbase + t] =
                es_red[0][t] + es_red[1][t] + es_red[2][t] + es_red[3][t];

        f32x4 acc2[4];
#pragma unroll
        for (int i = 0; i < 4; ++i) acc2[i] = (f32x4){0.f, 0.f, 0.f, 0.f};

#pragma unroll
        for (int ki = 0; ki < 8; ++ki) {
            bf16x8 pf = *(const bf16x8*)(
                P_s + lr * 256 + ((32 * ki + 8 * lc) ^ ((lr & 7) << 3)));
            const size_t tbase =
                ((size_t)((b * 32 + c * 8 + ki) * 16 + 4 * w) << 9) + l * 8;
#pragma unroll
            for (int dbi = 0; dbi < 4; ++dbi) {
                bf16x8 vf = *(const bf16x8*)(VB + tbase + ((size_t)dbi << 9));
                acc2[dbi] = __builtin_amdgcn_mfma_f32_16x16x32_bf16(pf, vf, acc2[dbi], 0, 0, 0);
            }
        }
#pragma unroll
        for (int dbi = 0; dbi < 4; ++dbi)
#pragma unroll
            for (int r = 0; r < 4; ++r)
                Opart[((size_t)c * (BB * SS) + rowbase + lc * 4 + r) * DD
                      + 64 * w + 16 * dbi + lr] = acc2[dbi][r];
    }
    grid.sync();

    // ---- Phase 3: combine + output projection (R8 body); all 512 blocks ----
    {
        float* inv_s = (float*)smem_raw;    // 64B
        const int r0 = (bx >> 2) * 16;
        const int ch = bx & 3;

        if (t < 16) {
            float d = 0.f;
#pragma unroll
            for (int c = 0; c < NCH; ++c) d += esum[(size_t)c * (BB * SS) + r0 + t];
            inv_s[t] = 1.f / d;
        }
        __syncthreads();

        const float inv = inv_s[lr];
        bf16x8 af[8];
#pragma unroll
        for (int db = 0; db < 8; ++db) {
            const float* op = Opart + (size_t)(r0 + lr) * DD + db * 32 + 8 * lc;
            float s0 = 0.f, s1 = 0.f, s2 = 0.f, s3 = 0.f;
            float s4 = 0.f, s5 = 0.f, s6 = 0.f, s7 = 0.f;
#pragma unroll
            for (int c = 0; c < NCH; ++c) {
                const float* p = op + (size_t)c * ((size_t)BB * SS * DD);
                float4 a0 = *(const float4*)(p);
                float4 a1 = *(const float4*)(p + 4);
                s0 += a0.x; s1 += a0.y; s2 += a0.z; s3 += a0.w;
                s4 += a1.x; s5 += a1.y; s6 += a1.z; s7 += a1.w;
            }
            bf16x8 a;
            a[0] = (short)f2bf(s0 * inv); a[1] = (short)f2bf(s1 * inv);
            a[2] = (short)f2bf(s2 * inv); a[3] = (short)f2bf(s3 * inv);
            a[4] = (short)f2bf(s4 * inv); a[5] = (short)f2bf(s5 * inv);
            a[6] = (short)f2bf(s6 * inv); a[7] = (short)f2bf(s7 * inv);
            af[db] = a;
        }

        const int jb = 64 * ch + 16 * w;
        f32x4 acc = {0.f, 0.f, 0.f, 0.f};
#pragma unroll
        for (int db = 0; db < 8; ++db) {
            bf16x8 bf = *(const bf16x8*)(Wob + (size_t)(jb + lr) * DD + db * 32 + 8 * lc);
            acc = __builtin_amdgcn_mfma_f32_16x16x32_bf16(af[db], bf, acc, 0, 0, 0);
        }
        const float bov = bo[jb + lr];
#pragma unroll
        for (int r = 0; r < 4; ++r)
            out[(size_t)(r0 + lc * 4 + r) * DD + jb + lr] = acc[r] + bov;
    }
}

// ===========================================================================
// FALLBACK: R8's four kernels, byte-identical, used only if the cooperative
// launch is rejected (capture or occupancy). Deterministic either way.
// ===========================================================================
__global__ __launch_bounds__(256) void cvt_bf16(
    const float* __restrict__ x,
    const float* __restrict__ Wq, const float* __restrict__ Wk,
    const float* __restrict__ Wv, const float* __restrict__ Wo,
    unsigned short* __restrict__ xb,
    unsigned short* __restrict__ Wqb, unsigned short* __restrict__ Wkb,
    unsigned short* __restrict__ Wvb, unsigned short* __restrict__ Wob)
{
    const int u = blockIdx.x * 256 + threadIdx.x;
    const float* src;
    unsigned short* dst;
    int base;
    if (u < 65536)      { src = x;  dst = xb;  base = u; }
    else if (u < 73728) { src = Wq; dst = Wqb; base = u - 65536; }
    else if (u < 81920) { src = Wk; dst = Wkb; base = u - 73728; }
    else if (u < 90112) { src = Wv; dst = Wvb; base = u - 81920; }
    else                { src = Wo; dst = Wob; base = u - 90112; }
    const float4* s4 = (const float4*)src + (size_t)base * 2;
    *(bf16x8*)(dst + (size_t)base * 8) = cvt8(s4[0], s4[1]);
}

__global__ __launch_bounds__(256, 2) void qkv_mfma(
    const unsigned short* __restrict__ xb,
    const unsigned short* __restrict__ Wqb, const float* __restrict__ bq,
    const unsigned short* __restrict__ Wkb, const float* __restrict__ bk,
    const unsigned short* __restrict__ Wvb, const float* __restrict__ bv,
    unsigned short* __restrict__ Qb, unsigned short* __restrict__ Kb,
    unsigned short* __restrict__ VB,
    float* __restrict__ qq, float* __restrict__ kk)
{
    __shared__ float red[4][16];
    const int t = threadIdx.x;
    const int w = t >> 6, l = t & 63, lr = l & 15, lc = l >> 4;
    const int mat = blockIdx.x % 3;
    const int tile = blockIdx.x / 3;
    const int r0 = tile * 16;
    const int b = r0 >> 10;
    const int s_in_base = r0 & (SS - 1);

    const unsigned short* W = (mat == 0) ? Wqb : (mat == 1) ? Wkb : Wvb;
    const float* bias       = (mat == 0) ? bq  : (mat == 1) ? bk  : bv;

    bf16x8 af[8];
#pragma unroll
    for (int db = 0; db < 8; ++db)
        af[db] = *(const bf16x8*)(xb + (size_t)(r0 + lr) * DD + db * 32 + 8 * lc);

    float nrm[4] = {0.f, 0.f, 0.f, 0.f};

#pragma unroll
    for (int cb = 0; cb < 4; ++cb) {
        const int jb = 64 * w + 16 * cb;
        f32x4 acc = {0.f, 0.f, 0.f, 0.f};
#pragma unroll
        for (int db = 0; db < 8; ++db) {
            bf16x8 bf = *(const bf16x8*)(W + (size_t)(jb + lr) * DD + db * 32 + 8 * lc);
            acc = __builtin_amdgcn_mfma_f32_16x16x32_bf16(af[db], bf, acc, 0, 0, 0);
        }
        const float bv_ = bias[jb + lr];
#pragma unroll
        for (int r = 0; r < 4; ++r) {
            const int srow = r0 + lc * 4 + r;
            const float v = acc[r] + bv_;
            const unsigned short h = f2bf(v);
            if (mat == 0) {
                Qb[(size_t)srow * DD + jb + lr] = h;
                const float hv = bf2f(h); nrm[r] += hv * hv;
            } else if (mat == 1) {
                Kb[(size_t)srow * DD + jb + lr] = h;
                const float hv = bf2f(h); nrm[r] += hv * hv;
            } else {
                const int s_in = s_in_base + lc * 4 + r;
                const int kb32 = s_in >> 5;
                const int kslot = (s_in >> 3) & 3;
                const int jj = s_in & 7;
                const int db16 = 4 * w + cb;
                const size_t off = ((size_t)((b * 32 + kb32) * 16 + db16) << 9)
                                 + ((kslot * 16 + lr) << 3) + jj;
                VB[off] = h;
            }
        }
    }

    if (mat < 2) {
#pragma unroll
        for (int r = 0; r < 4; ++r) {
            float n = nrm[r];
#pragma unroll
            for (int m = 1; m < 16; m <<= 1) n += __shfl_xor(n, m, 64);
            if (lr == 0) red[w][lc * 4 + r] = n;
        }
        __syncthreads();
        if (t < 16) {
            const float s = red[0][t] + red[1][t] + red[2][t] + red[3][t];
            if (mat == 0) qq[r0 + t] = s;
            else          kk[r0 + t] = s;
        }
    }
}

__global__ __launch_bounds__(256, 2) void attn_part_mfma(
    const unsigned short* __restrict__ Qb, const unsigned short* __restrict__ Kb,
    const unsigned short* __restrict__ VB,
    const float* __restrict__ qq, const float* __restrict__ kk,
    float* __restrict__ Opart, float* __restrict__ esum)
{
    __shared__ unsigned short P_s[16 * 256];
    __shared__ float kk_s[KCH];
    __shared__ float qq_s[16];
    __shared__ float es_red[4][16];

    const int t = threadIdx.x;
    const int w = t >> 6, l = t & 63, lr = l & 15, lc = l >> 4;
    const int qtile = blockIdx.x >> 2;
    const int c = blockIdx.x & 3;
    const int rowbase = qtile * 16;
    const int b = rowbase >> 10;
    const int s0 = c * KCH;

    kk_s[t] = kk[b * SS + s0 + t];
    if (t < 16) qq_s[t] = qq[rowbase + t];

    bf16x8 qf[8];
#pragma unroll
    for (int db = 0; db < 8; ++db)
        qf[db] = *(const bf16x8*)(Qb + (size_t)(rowbase + lr) * DD + db * 32 + 8 * lc);

    __syncthreads();

    float psum[4] = {0.f, 0.f, 0.f, 0.f};
#pragma unroll
    for (int kbi = 0; kbi < 4; ++kbi) {
        const int kb = 64 * w + 16 * kbi;
        f32x4 acc = {0.f, 0.f, 0.f, 0.f};
#pragma unroll
        for (int db = 0; db < 8; ++db) {
            bf16x8 kf = *(const bf16x8*)(
                Kb + (size_t)(b * SS + s0 + kb + lr) * DD + db * 32 + 8 * lc);
            acc = __builtin_amdgcn_mfma_f32_16x16x32_bf16(qf[db], kf, acc, 0, 0, 0);
        }
        const int kcol = kb + lr;
        const float kkv = kk_s[kcol];
#pragma unroll
        for (int r = 0; r < 4; ++r) {
            const int qi = lc * 4 + r;
            const float d2 = fmaxf(qq_s[qi] + kkv - 2.f * acc[r], 0.f);
            const float e = __expf(-sqrtf(d2) * 0.0625f);
            psum[r] += e;
            P_s[qi * 256 + (kcol ^ ((qi & 7) << 3))] = f2bf(e);
        }
    }
#pragma unroll
    for (int r = 0; r < 4; ++r) {
        float s = psum[r];
#pragma unroll
        for (int m = 1; m < 16; m <<= 1) s += __shfl_xor(s, m, 64);
        if (lr == 0) es_red[w][lc * 4 + r] = s;
    }
    __syncthreads();
    if (t < 16)
        esum[(size_t)c * (BB * SS) + rowbase + t] =
            es_red[0][t] + es_red[1][t] + es_red[2][t] + es_red[3][t];

    f32x4 acc2[4];
#pragma unroll
    for (int i = 0; i < 4; ++i) acc2[i] = (f32x4){0.f, 0.f, 0.f, 0.f};

#pragma unroll
    for (int ki = 0; ki < 8; ++ki) {
        bf16x8 pf = *(const bf16x8*)(
            P_s + lr * 256 + ((32 * ki + 8 * lc) ^ ((lr & 7) << 3)));
        const size_t tbase =
            ((size_t)((b * 32 + c * 8 + ki) * 16 + 4 * w) << 9) + l * 8;
#pragma unroll
        for (int dbi = 0; dbi < 4; ++dbi) {
            bf16x8 vf = *(const bf16x8*)(VB + tbase + ((size_t)dbi << 9));
            acc2[dbi] = __builtin_amdgcn_mfma_f32_16x16x32_bf16(pf, vf, acc2[dbi], 0, 0, 0);
        }
    }
#pragma unroll
    for (int dbi = 0; dbi < 4; ++dbi)
#pragma unroll
        for (int r = 0; r < 4; ++r)
            Opart[((size_t)c * (BB * SS) + rowbase + lc * 4 + r) * DD
                  + 64 * w + 16 * dbi + lr] = acc2[dbi][r];
}

__global__ __launch_bounds__(256, 2) void combine_mfma(
    const float* __restrict__ Opart, const float* __restrict__ esum,
    const unsigned short* __restrict__ Wob, const float* __restrict__ bo,
    float* __restrict__ out)
{
    __shared__ float inv_s[16];
    const int t = threadIdx.x;
    const int w = t >> 6, l = t & 63, lr = l & 15, lc = l >> 4;
    const int r0 = (blockIdx.x >> 2) * 16;
    const int ch = blockIdx.x & 3;

    if (t < 16) {
        float d = 0.f;
#pragma unroll
        for (int c = 0; c < NCH; ++c) d += esum[(size_t)c * (BB * SS) + r0 + t];
        inv_s[t] = 1.f / d;
    }
    __syncthreads();

    const float inv = inv_s[lr];
    bf16x8 af[8];
#pragma unroll
    for (int db = 0; db < 8; ++db) {
        const float* op = Opart + (size_t)(r0 + lr) * DD + db * 32 + 8 * lc;
        float s0 = 0.f, s1 = 0.f, s2 = 0.f, s3 = 0.f;
        float s4 = 0.f, s5 = 0.f, s6 = 0.f, s7 = 0.f;
#pragma unroll
        for (int c = 0; c < NCH; ++c) {
            const float* p = op + (size_t)c * ((size_t)BB * SS * DD);
            float4 a0 = *(const float4*)(p);
            float4 a1 = *(const float4*)(p + 4);
            s0 += a0.x; s1 += a0.y; s2 += a0.z; s3 += a0.w;
            s4 += a1.x; s5 += a1.y; s6 += a1.z; s7 += a1.w;
        }
        bf16x8 a;
        a[0] = (short)f2bf(s0 * inv); a[1] = (short)f2bf(s1 * inv);
        a[2] = (short)f2bf(s2 * inv); a[3] = (short)f2bf(s3 * inv);
        a[4] = (short)f2bf(s4 * inv); a[5] = (short)f2bf(s5 * inv);
        a[6] = (short)f2bf(s6 * inv); a[7] = (short)f2bf(s7 * inv);
        af[db] = a;
    }

    const int jb = 64 * ch + 16 * w;
    f32x4 acc = {0.f, 0.f, 0.f, 0.f};
#pragma unroll
    for (int db = 0; db < 8; ++db) {
        bf16x8 bf = *(const bf16x8*)(Wob + (size_t)(jb + lr) * DD + db * 32 + 8 * lc);
        acc = __builtin_amdgcn_mfma_f32_16x16x32_bf16(af[db], bf, acc, 0, 0, 0);
    }
    const float bov = bo[jb + lr];
#pragma unroll
    for (int r = 0; r < 4; ++r)
        out[(size_t)(r0 + lc * 4 + r) * DD + jb + lr] = acc[r] + bov;
}

// ---------------------------------------------------------------------------
extern "C" void kernel_launch(void* const* d_in, const int* in_sizes, int n_in,
                              void* d_out, int out_size, void* d_ws, size_t ws_size,
                              hipStream_t stream) {
    const float* x  = (const float*)d_in[0];
    const float* Wq = (const float*)d_in[1];
    const float* bq = (const float*)d_in[2];
    const float* Wk = (const float*)d_in[3];
    const float* bk = (const float*)d_in[4];
    const float* Wv = (const float*)d_in[5];
    const float* bv = (const float*)d_in[6];
    const float* Wo = (const float*)d_in[7];
    const float* bo = (const float*)d_in[8];
    float* out = (float*)d_out;
    unsigned char* ws = (unsigned char*)d_ws;

    // cooperative fused launch (512 blocks x 256 thr, 2 blocks/CU)
    void* args[] = {
        (void*)&x, (void*)&Wq, (void*)&bq, (void*)&Wk, (void*)&bk,
        (void*)&Wv, (void*)&bv, (void*)&Wo, (void*)&bo, (void*)&out, (void*)&ws
    };
    hipError_t err = hipLaunchCooperativeKernel(
        (void*)geo_fused, dim3(512), dim3(256), args, 0, stream);

    if (err != hipSuccess) {
        // fallback: R8's four-kernel path (identical numerics)
        const size_t rows = (size_t)BB * SS;
        unsigned short* Qb  = (unsigned short*)d_ws;
        unsigned short* Kb  = Qb + rows * DD;
        unsigned short* VB  = Kb + rows * DD;
        unsigned short* xb  = VB + rows * DD;
        unsigned short* Wqb = xb + rows * DD;
        unsigned short* Wkb = Wqb + (size_t)DD * DD;
        unsigned short* Wvb = Wkb + (size_t)DD * DD;
        unsigned short* Wob = Wvb + (size_t)DD * DD;
        float* qq    = (float*)(Wob + (size_t)DD * DD);
        float* kk    = qq + rows;
        float* esum  = kk + rows;
        float* Opart = esum + (size_t)NCH * rows;

        cvt_bf16<<<384, 256, 0, stream>>>(x, Wq, Wk, Wv, Wo,
                                          xb, Wqb, Wkb, Wvb, Wob);
        qkv_mfma<<<(int)(rows / 16) * 3, 256, 0, stream>>>(
            xb, Wqb, bq, Wkb, bk, Wvb, bv, Qb, Kb, VB, qq, kk);
        attn_part_mfma<<<(int)(rows / 16) * NCH, 256, 0, stream>>>(
            Qb, Kb, VB, qq, kk, Opart, esum);
        combine_mfma<<<(int)(rows / 16) * 4, 256, 0, stream>>>(
            Opart, esum, Wob, bo, out);
    }
}

// Round 12
// 59.858 us; speedup vs baseline: 4.0936x; 4.0936x over previous
//
#include <hip/hip_runtime.h>
#include <hip/hip_bf16.h>

#define BB 2
#define SS 1024
#define DD 256
#define NCH 4           // k-chunks in attn
#define KCH 256         // k-chunk size

typedef __attribute__((ext_vector_type(8))) short bf16x8;
typedef __attribute__((ext_vector_type(4))) float f32x4;

__device__ __forceinline__ unsigned short f2bf(float f) {
    __hip_bfloat16 h = __float2bfloat16(f);
    return *reinterpret_cast<unsigned short*>(&h);
}
__device__ __forceinline__ float bf2f(unsigned short u) {
    __hip_bfloat16 h;
    *reinterpret_cast<unsigned short*>(&h) = u;
    return __bfloat162float(h);
}
__device__ __forceinline__ bf16x8 cvt8(float4 f0, float4 f1) {
    bf16x8 o;
    o[0] = (short)f2bf(f0.x); o[1] = (short)f2bf(f0.y);
    o[2] = (short)f2bf(f0.z); o[3] = (short)f2bf(f0.w);
    o[4] = (short)f2bf(f1.x); o[5] = (short)f2bf(f1.y);
    o[6] = (short)f2bf(f1.z); o[7] = (short)f2bf(f1.w);
    return o;
}

// ---------------------------------------------------------------------------
// Kernel 0: one-pass fp32->bf16 conversion (byte-identical to round 8).
// ---------------------------------------------------------------------------
__global__ __launch_bounds__(256) void cvt_bf16(
    const float* __restrict__ x,
    const float* __restrict__ Wq, const float* __restrict__ Wk,
    const float* __restrict__ Wv, const float* __restrict__ Wo,
    unsigned short* __restrict__ xb,
    unsigned short* __restrict__ Wqb, unsigned short* __restrict__ Wkb,
    unsigned short* __restrict__ Wvb, unsigned short* __restrict__ Wob)
{
    const int u = blockIdx.x * 256 + threadIdx.x;
    const float* src;
    unsigned short* dst;
    int base;
    if (u < 65536)      { src = x;  dst = xb;  base = u; }
    else if (u < 73728) { src = Wq; dst = Wqb; base = u - 65536; }
    else if (u < 81920) { src = Wk; dst = Wkb; base = u - 73728; }
    else if (u < 90112) { src = Wv; dst = Wvb; base = u - 81920; }
    else                { src = Wo; dst = Wob; base = u - 90112; }
    const float4* s4 = (const float4*)src + (size_t)base * 2;
    *(bf16x8*)(dst + (size_t)base * 8) = cvt8(s4[0], s4[1]);
}

// ---------------------------------------------------------------------------
// Kernel 1: QKV projection via MFMA -- 512-thread (8-wave) TLP version.
// grid = 384 blocks (same); wave w owns 32 out-cols (jb = 32w + 16cb, cb<2).
// Same total work, 2x the waves: 3072 waves = 3 waves/SIMD (was 1.5-2).
// ---------------------------------------------------------------------------
__global__ __launch_bounds__(512, 4) void qkv_mfma(
    const unsigned short* __restrict__ xb,
    const unsigned short* __restrict__ Wqb, const float* __restrict__ bq,
    const unsigned short* __restrict__ Wkb, const float* __restrict__ bk,
    const unsigned short* __restrict__ Wvb, const float* __restrict__ bv,
    unsigned short* __restrict__ Qb, unsigned short* __restrict__ Kb,
    unsigned short* __restrict__ VB,
    float* __restrict__ qq, float* __restrict__ kk)
{
    __shared__ float red[8][16];
    const int t = threadIdx.x;
    const int w = t >> 6, l = t & 63, lr = l & 15, lc = l >> 4;
    const int mat = blockIdx.x % 3;
    const int tile = blockIdx.x / 3;
    const int r0 = tile * 16;                 // global seq row (incl. batch)
    const int b = r0 >> 10;
    const int s_in_base = r0 & (SS - 1);

    const unsigned short* W = (mat == 0) ? Wqb : (mat == 1) ? Wkb : Wvb;
    const float* bias       = (mat == 0) ? bq  : (mat == 1) ? bk  : bv;

    // A-frags from xb: lane(row=l%16, 8 contiguous d)
    bf16x8 af[8];
#pragma unroll
    for (int db = 0; db < 8; ++db)
        af[db] = *(const bf16x8*)(xb + (size_t)(r0 + lr) * DD + db * 32 + 8 * lc);

    float nrm[4] = {0.f, 0.f, 0.f, 0.f};

#pragma unroll
    for (int cb = 0; cb < 2; ++cb) {
        const int jb = 32 * w + 16 * cb;
        f32x4 acc = {0.f, 0.f, 0.f, 0.f};
#pragma unroll
        for (int db = 0; db < 8; ++db) {
            bf16x8 bf = *(const bf16x8*)(W + (size_t)(jb + lr) * DD + db * 32 + 8 * lc);
            acc = __builtin_amdgcn_mfma_f32_16x16x32_bf16(af[db], bf, acc, 0, 0, 0);
        }
        const float bv_ = bias[jb + lr];
#pragma unroll
        for (int r = 0; r < 4; ++r) {
            const int srow = r0 + lc * 4 + r;     // C/D: row=(l>>4)*4+r, col=l%16
            const float v = acc[r] + bv_;
            const unsigned short h = f2bf(v);
            if (mat == 0) {
                Qb[(size_t)srow * DD + jb + lr] = h;
                const float hv = bf2f(h); nrm[r] += hv * hv;
            } else if (mat == 1) {
                Kb[(size_t)srow * DD + jb + lr] = h;
                const float hv = bf2f(h); nrm[r] += hv * hv;
            } else {
                // VB layout: tile(b, kb32=s/32, db16=d/16) of 1024B
                const int s_in = s_in_base + lc * 4 + r;
                const int kb32 = s_in >> 5;
                const int kslot = (s_in >> 3) & 3;
                const int jj = s_in & 7;
                const int db16 = 2 * w + cb;      // 8 waves x 2 cb = 16
                const size_t off = ((size_t)((b * 32 + kb32) * 16 + db16) << 9)
                                 + ((kslot * 16 + lr) << 3) + jj;
                VB[off] = h;
            }
        }
    }

    if (mat < 2) {
#pragma unroll
        for (int r = 0; r < 4; ++r) {
            float n = nrm[r];
#pragma unroll
            for (int m = 1; m < 16; m <<= 1) n += __shfl_xor(n, m, 64);
            if (lr == 0) red[w][lc * 4 + r] = n;
        }
        __syncthreads();
        if (t < 16) {
            float s = 0.f;
#pragma unroll
            for (int ww = 0; ww < 8; ++ww) s += red[ww][t];
            if (mat == 0) qq[r0 + t] = s;
            else          kk[r0 + t] = s;
        }
    }
}

// ---------------------------------------------------------------------------
// Kernel 2: partial attention via MFMA -- 512-thread (8-wave) TLP version.
// grid = 512 blocks (same). QK^T: wave w owns k-cols [32w,32w+32) (2 kbi).
// PV: wave w owns d-cols [32w,32w+32) (2 dbi). 4096 waves = 4 waves/SIMD.
// Same total MFMA work and numerics as R8; waves just repartition columns.
// ---------------------------------------------------------------------------
__global__ __launch_bounds__(512, 4) void attn_part_mfma(
    const unsigned short* __restrict__ Qb, const unsigned short* __restrict__ Kb,
    const unsigned short* __restrict__ VB,
    const float* __restrict__ qq, const float* __restrict__ kk,
    float* __restrict__ Opart, float* __restrict__ esum)
{
    __shared__ unsigned short P_s[16 * 256];   // 8 KB, XOR-swizzled
    __shared__ float kk_s[KCH];
    __shared__ float qq_s[16];
    __shared__ float es_red[8][16];

    const int t = threadIdx.x;
    const int w = t >> 6, l = t & 63, lr = l & 15, lc = l >> 4;
    const int qtile = blockIdx.x >> 2;
    const int c = blockIdx.x & 3;
    const int rowbase = qtile * 16;            // global row
    const int b = rowbase >> 10;
    const int s0 = c * KCH;                    // chunk start within batch

    if (t < KCH) kk_s[t] = kk[b * SS + s0 + t];
    if (t < 16) qq_s[t] = qq[rowbase + t];

    // Q A-frags: lane(row=l%16, 8 contiguous d)
    bf16x8 qf[8];
#pragma unroll
    for (int db = 0; db < 8; ++db)
        qf[db] = *(const bf16x8*)(Qb + (size_t)(rowbase + lr) * DD + db * 32 + 8 * lc);

    __syncthreads();

    // ---- QK^T + exp: wave w owns k-cols [32w, 32w+32) ----
    float psum[4] = {0.f, 0.f, 0.f, 0.f};
#pragma unroll
    for (int kbi = 0; kbi < 2; ++kbi) {
        const int kb = 32 * w + 16 * kbi;
        f32x4 acc = {0.f, 0.f, 0.f, 0.f};
#pragma unroll
        for (int db = 0; db < 8; ++db) {
            bf16x8 kf = *(const bf16x8*)(
                Kb + (size_t)(b * SS + s0 + kb + lr) * DD + db * 32 + 8 * lc);
            acc = __builtin_amdgcn_mfma_f32_16x16x32_bf16(qf[db], kf, acc, 0, 0, 0);
        }
        const int kcol = kb + lr;
        const float kkv = kk_s[kcol];
#pragma unroll
        for (int r = 0; r < 4; ++r) {
            const int qi = lc * 4 + r;
            const float d2 = fmaxf(qq_s[qi] + kkv - 2.f * acc[r], 0.f);
            const float e = __expf(-sqrtf(d2) * 0.0625f);
            psum[r] += e;
            P_s[qi * 256 + (kcol ^ ((qi & 7) << 3))] = f2bf(e);
        }
    }
    // per-row e-sums: reduce across l%16, then across 8 waves via LDS
#pragma unroll
    for (int r = 0; r < 4; ++r) {
        float s = psum[r];
#pragma unroll
        for (int m = 1; m < 16; m <<= 1) s += __shfl_xor(s, m, 64);
        if (lr == 0) es_red[w][lc * 4 + r] = s;
    }
    __syncthreads();   // also publishes P_s for PV
    if (t < 16) {
        float s = 0.f;
#pragma unroll
        for (int ww = 0; ww < 8; ++ww) s += es_red[ww][t];
        esum[(size_t)c * (BB * SS) + rowbase + t] = s;
    }

    // ---- PV: wave w owns d-cols [32w, 32w+32) ----
    f32x4 acc2[2];
#pragma unroll
    for (int i = 0; i < 2; ++i) acc2[i] = (f32x4){0.f, 0.f, 0.f, 0.f};

#pragma unroll
    for (int ki = 0; ki < 8; ++ki) {
        // A = P: lane(row q=l%16, k = 32ki + 8*(l>>4) + j), swizzled read
        bf16x8 pf = *(const bf16x8*)(
            P_s + lr * 256 + ((32 * ki + 8 * lc) ^ ((lr & 7) << 3)));
        const size_t tbase =
            ((size_t)((b * 32 + c * 8 + ki) * 16 + 2 * w) << 9) + l * 8;
#pragma unroll
        for (int dbi = 0; dbi < 2; ++dbi) {
            bf16x8 vf = *(const bf16x8*)(VB + tbase + ((size_t)dbi << 9));
            acc2[dbi] = __builtin_amdgcn_mfma_f32_16x16x32_bf16(pf, vf, acc2[dbi], 0, 0, 0);
        }
    }
#pragma unroll
    for (int dbi = 0; dbi < 2; ++dbi)
#pragma unroll
        for (int r = 0; r < 4; ++r)
            Opart[((size_t)c * (BB * SS) + rowbase + lc * 4 + r) * DD
                  + 32 * w + 16 * dbi + lr] = acc2[dbi][r];
}

// ---------------------------------------------------------------------------
// Kernel 3: combine + output projection via MFMA (byte-identical to round 8).
// ---------------------------------------------------------------------------
__global__ __launch_bounds__(256, 2) void combine_mfma(
    const float* __restrict__ Opart, const float* __restrict__ esum,
    const unsigned short* __restrict__ Wob, const float* __restrict__ bo,
    float* __restrict__ out)
{
    __shared__ float inv_s[16];
    const int t = threadIdx.x;
    const int w = t >> 6, l = t & 63, lr = l & 15, lc = l >> 4;
    const int r0 = (blockIdx.x >> 2) * 16;   // global row
    const int ch = blockIdx.x & 3;           // col quarter

    if (t < 16) {
        float d = 0.f;
#pragma unroll
        for (int c = 0; c < NCH; ++c) d += esum[(size_t)c * (BB * SS) + r0 + t];
        inv_s[t] = 1.f / d;
    }
    __syncthreads();

    const float inv = inv_s[lr];
    bf16x8 af[8];
#pragma unroll
    for (int db = 0; db < 8; ++db) {
        const float* op = Opart + (size_t)(r0 + lr) * DD + db * 32 + 8 * lc;
        float s0 = 0.f, s1 = 0.f, s2 = 0.f, s3 = 0.f;
        float s4 = 0.f, s5 = 0.f, s6 = 0.f, s7 = 0.f;
#pragma unroll
        for (int c = 0; c < NCH; ++c) {
            const float* p = op + (size_t)c * ((size_t)BB * SS * DD);
            float4 a0 = *(const float4*)(p);
            float4 a1 = *(const float4*)(p + 4);
            s0 += a0.x; s1 += a0.y; s2 += a0.z; s3 += a0.w;
            s4 += a1.x; s5 += a1.y; s6 += a1.z; s7 += a1.w;
        }
        bf16x8 a;
        a[0] = (short)f2bf(s0 * inv); a[1] = (short)f2bf(s1 * inv);
        a[2] = (short)f2bf(s2 * inv); a[3] = (short)f2bf(s3 * inv);
        a[4] = (short)f2bf(s4 * inv); a[5] = (short)f2bf(s5 * inv);
        a[6] = (short)f2bf(s6 * inv); a[7] = (short)f2bf(s7 * inv);
        af[db] = a;
    }

    const int jb = 64 * ch + 16 * w;
    f32x4 acc = {0.f, 0.f, 0.f, 0.f};
#pragma unroll
    for (int db = 0; db < 8; ++db) {
        bf16x8 bf = *(const bf16x8*)(Wob + (size_t)(jb + lr) * DD + db * 32 + 8 * lc);
        acc = __builtin_amdgcn_mfma_f32_16x16x32_bf16(af[db], bf, acc, 0, 0, 0);
    }
    const float bov = bo[jb + lr];
#pragma unroll
    for (int r = 0; r < 4; ++r)
        out[(size_t)(r0 + lc * 4 + r) * DD + jb + lr] = acc[r] + bov;
}

// ---------------------------------------------------------------------------
extern "C" void kernel_launch(void* const* d_in, const int* in_sizes, int n_in,
                              void* d_out, int out_size, void* d_ws, size_t ws_size,
                              hipStream_t stream) {
    const float* x  = (const float*)d_in[0];
    const float* Wq = (const float*)d_in[1];
    const float* bq = (const float*)d_in[2];
    const float* Wk = (const float*)d_in[3];
    const float* bk = (const float*)d_in[4];
    const float* Wv = (const float*)d_in[5];
    const float* bv = (const float*)d_in[6];
    const float* Wo = (const float*)d_in[7];
    const float* bo = (const float*)d_in[8];
    float* out = (float*)d_out;

    // ws layout (bf16 first, then fp32):
    // Qb | Kb | VB | xb | Wqb | Wkb | Wvb | Wob || qq | kk | esum | Opart
    const size_t rows = (size_t)BB * SS;            // 2048
    unsigned short* Qb  = (unsigned short*)d_ws;
    unsigned short* Kb  = Qb + rows * DD;
    unsigned short* VB  = Kb + rows * DD;
    unsigned short* xb  = VB + rows * DD;
    unsigned short* Wqb = xb + rows * DD;
    unsigned short* Wkb = Wqb + (size_t)DD * DD;
    unsigned short* Wvb = Wkb + (size_t)DD * DD;
    unsigned short* Wob = Wvb + (size_t)DD * DD;
    float* qq    = (float*)(Wob + (size_t)DD * DD);
    float* kk    = qq + rows;
    float* esum  = kk + rows;
    float* Opart = esum + (size_t)NCH * rows;       // NCH*rows*DD floats

    cvt_bf16<<<384, 256, 0, stream>>>(x, Wq, Wk, Wv, Wo,
                                      xb, Wqb, Wkb, Wvb, Wob);
    qkv_mfma<<<(int)(rows / 16) * 3, 512, 0, stream>>>(
        xb, Wqb, bq, Wkb, bk, Wvb, bv, Qb, Kb, VB, qq, kk);
    attn_part_mfma<<<(int)(rows / 16) * NCH, 512, 0, stream>>>(
        Qb, Kb, VB, qq, kk, Opart, esum);
    combine_mfma<<<(int)(rows / 16) * 4, 256, 0, stream>>>(
        Opart, esum, Wob, bo, out);
}

// Round 13
// 51.414 us; speedup vs baseline: 4.7659x; 1.1642x over previous
//
#include <hip/hip_runtime.h>
#include <hip/hip_bf16.h>

#define BB 2
#define SS 1024
#define DD 256

typedef __attribute__((ext_vector_type(8))) short bf16x8;
typedef __attribute__((ext_vector_type(4))) float f32x4;

__device__ __forceinline__ unsigned short f2bf(float f) {
    __hip_bfloat16 h = __float2bfloat16(f);
    return *reinterpret_cast<unsigned short*>(&h);
}
__device__ __forceinline__ float bf2f(unsigned short u) {
    __hip_bfloat16 h;
    *reinterpret_cast<unsigned short*>(&h) = u;
    return __bfloat162float(h);
}
__device__ __forceinline__ bf16x8 cvt8(float4 f0, float4 f1) {
    bf16x8 o;
    o[0] = (short)f2bf(f0.x); o[1] = (short)f2bf(f0.y);
    o[2] = (short)f2bf(f0.z); o[3] = (short)f2bf(f0.w);
    o[4] = (short)f2bf(f1.x); o[5] = (short)f2bf(f1.y);
    o[6] = (short)f2bf(f1.z); o[7] = (short)f2bf(f1.w);
    return o;
}

// ---------------------------------------------------------------------------
// Kernel 0: one-pass fp32->bf16 conversion (byte-identical to round 8).
// ---------------------------------------------------------------------------
__global__ __launch_bounds__(256) void cvt_bf16(
    const float* __restrict__ x,
    const float* __restrict__ Wq, const float* __restrict__ Wk,
    const float* __restrict__ Wv, const float* __restrict__ Wo,
    unsigned short* __restrict__ xb,
    unsigned short* __restrict__ Wqb, unsigned short* __restrict__ Wkb,
    unsigned short* __restrict__ Wvb, unsigned short* __restrict__ Wob)
{
    const int u = blockIdx.x * 256 + threadIdx.x;
    const float* src;
    unsigned short* dst;
    int base;
    if (u < 65536)      { src = x;  dst = xb;  base = u; }
    else if (u < 73728) { src = Wq; dst = Wqb; base = u - 65536; }
    else if (u < 81920) { src = Wk; dst = Wkb; base = u - 73728; }
    else if (u < 90112) { src = Wv; dst = Wvb; base = u - 81920; }
    else                { src = Wo; dst = Wob; base = u - 90112; }
    const float4* s4 = (const float4*)src + (size_t)base * 2;
    *(bf16x8*)(dst + (size_t)base * 8) = cvt8(s4[0], s4[1]);
}

// ---------------------------------------------------------------------------
// Kernel 1: QKV projection via MFMA (byte-identical to round 8, 256 thr).
// ---------------------------------------------------------------------------
__global__ __launch_bounds__(256, 2) void qkv_mfma(
    const unsigned short* __restrict__ xb,
    const unsigned short* __restrict__ Wqb, const float* __restrict__ bq,
    const unsigned short* __restrict__ Wkb, const float* __restrict__ bk,
    const unsigned short* __restrict__ Wvb, const float* __restrict__ bv,
    unsigned short* __restrict__ Qb, unsigned short* __restrict__ Kb,
    unsigned short* __restrict__ VB,
    float* __restrict__ qq, float* __restrict__ kk)
{
    __shared__ float red[4][16];
    const int t = threadIdx.x;
    const int w = t >> 6, l = t & 63, lr = l & 15, lc = l >> 4;
    const int mat = blockIdx.x % 3;
    const int tile = blockIdx.x / 3;
    const int r0 = tile * 16;
    const int b = r0 >> 10;
    const int s_in_base = r0 & (SS - 1);

    const unsigned short* W = (mat == 0) ? Wqb : (mat == 1) ? Wkb : Wvb;
    const float* bias       = (mat == 0) ? bq  : (mat == 1) ? bk  : bv;

    bf16x8 af[8];
#pragma unroll
    for (int db = 0; db < 8; ++db)
        af[db] = *(const bf16x8*)(xb + (size_t)(r0 + lr) * DD + db * 32 + 8 * lc);

    float nrm[4] = {0.f, 0.f, 0.f, 0.f};

#pragma unroll
    for (int cb = 0; cb < 4; ++cb) {
        const int jb = 64 * w + 16 * cb;
        f32x4 acc = {0.f, 0.f, 0.f, 0.f};
#pragma unroll
        for (int db = 0; db < 8; ++db) {
            bf16x8 bf = *(const bf16x8*)(W + (size_t)(jb + lr) * DD + db * 32 + 8 * lc);
            acc = __builtin_amdgcn_mfma_f32_16x16x32_bf16(af[db], bf, acc, 0, 0, 0);
        }
        const float bv_ = bias[jb + lr];
#pragma unroll
        for (int r = 0; r < 4; ++r) {
            const int srow = r0 + lc * 4 + r;
            const float v = acc[r] + bv_;
            const unsigned short h = f2bf(v);
            if (mat == 0) {
                Qb[(size_t)srow * DD + jb + lr] = h;
                const float hv = bf2f(h); nrm[r] += hv * hv;
            } else if (mat == 1) {
                Kb[(size_t)srow * DD + jb + lr] = h;
                const float hv = bf2f(h); nrm[r] += hv * hv;
            } else {
                const int s_in = s_in_base + lc * 4 + r;
                const int kb32 = s_in >> 5;
                const int kslot = (s_in >> 3) & 3;
                const int jj = s_in & 7;
                const int db16 = 4 * w + cb;
                const size_t off = ((size_t)((b * 32 + kb32) * 16 + db16) << 9)
                                 + ((kslot * 16 + lr) << 3) + jj;
                VB[off] = h;
            }
        }
    }

    if (mat < 2) {
#pragma unroll
        for (int r = 0; r < 4; ++r) {
            float n = nrm[r];
#pragma unroll
            for (int m = 1; m < 16; m <<= 1) n += __shfl_xor(n, m, 64);
            if (lr == 0) red[w][lc * 4 + r] = n;
        }
        __syncthreads();
        if (t < 16) {
            const float s = red[0][t] + red[1][t] + red[2][t] + red[3][t];
            if (mat == 0) qq[r0 + t] = s;
            else          kk[r0 + t] = s;
        }
    }
}

// ---------------------------------------------------------------------------
// Kernel 2: FUSED attention + output projection, full k-range per block.
// grid = 128 blocks (one per 16-row q-tile), 512 threads (8 waves).
// No max-pass needed (e in (0,1]) -> one block owns the complete row sum ->
// normalize locally and do out-proj in-block. Eliminates Opart (42MB of
// cross-XCD traffic), esum, and the combine kernel + launch.
//   Phase A: wave w owns k-cols [128w,128w+128): 8 kbi x 8 db MFMA -> e,
//            P_s[16][1024] bf16 XOR-swizzled (proven formula; row stride
//            2048B = 0 mod 128B -> same bank structure as R8's P_s).
//   row sums: lr-shuffle reduce + cross-wave LDS -> inv_s[16].
//   Phase B: wave w owns att-d cols [32w,32w+32): 32 ki x 2 dbi MFMA.
//   att redistribution: normalized bf16 att -> att_s[16][264] (padded).
//   Phase C: wave w owns out-cols [32w,32w+32): 2 cb x 8 db MFMA + bias.
// ---------------------------------------------------------------------------
__global__ __launch_bounds__(512, 2) void attn_out_mfma(
    const unsigned short* __restrict__ Qb, const unsigned short* __restrict__ Kb,
    const unsigned short* __restrict__ VB,
    const float* __restrict__ qq, const float* __restrict__ kk,
    const unsigned short* __restrict__ Wob, const float* __restrict__ bo,
    float* __restrict__ out)
{
    __shared__ __align__(16) unsigned short P_s[16 * 1024];  // 32 KB
    __shared__ float kk_s[SS];                               // 4 KB
    __shared__ float qq_s[16];
    __shared__ float es_red[8][16];
    __shared__ float inv_s[16];
    unsigned short* att_s = P_s;     // reuse after PV: [16][264] padded

    const int t = threadIdx.x;
    const int w = t >> 6, l = t & 63, lr = l & 15, lc = l >> 4;
    const int rowbase = blockIdx.x * 16;       // global row
    const int b = rowbase >> 10;

    kk_s[t] = kk[b * SS + t];
    kk_s[t + 512] = kk[b * SS + t + 512];
    if (t < 16) qq_s[t] = qq[rowbase + t];

    // Q A-frags: lane(row=l%16, 8 contiguous d)
    bf16x8 qf[8];
#pragma unroll
    for (int db = 0; db < 8; ++db)
        qf[db] = *(const bf16x8*)(Qb + (size_t)(rowbase + lr) * DD + db * 32 + 8 * lc);

    __syncthreads();

    // ---- Phase A: QK^T + exp; wave w owns k-cols [128w, 128w+128) ----
    float psum[4] = {0.f, 0.f, 0.f, 0.f};
#pragma unroll
    for (int kbi = 0; kbi < 8; ++kbi) {
        const int kb = 128 * w + 16 * kbi;
        f32x4 acc = {0.f, 0.f, 0.f, 0.f};
#pragma unroll
        for (int db = 0; db < 8; ++db) {
            bf16x8 kf = *(const bf16x8*)(
                Kb + (size_t)(b * SS + kb + lr) * DD + db * 32 + 8 * lc);
            acc = __builtin_amdgcn_mfma_f32_16x16x32_bf16(qf[db], kf, acc, 0, 0, 0);
        }
        const int kcol = kb + lr;
        const float kkv = kk_s[kcol];
#pragma unroll
        for (int r = 0; r < 4; ++r) {
            const int qi = lc * 4 + r;
            const float d2 = fmaxf(qq_s[qi] + kkv - 2.f * acc[r], 0.f);
            const float e = __expf(-sqrtf(d2) * 0.0625f);
            psum[r] += e;
            P_s[qi * 1024 + (kcol ^ ((qi & 7) << 3))] = f2bf(e);
        }
    }
    // per-row sums: reduce across lr (16), then across 8 waves via LDS
#pragma unroll
    for (int r = 0; r < 4; ++r) {
        float s = psum[r];
#pragma unroll
        for (int m = 1; m < 16; m <<= 1) s += __shfl_xor(s, m, 64);
        if (lr == 0) es_red[w][lc * 4 + r] = s;
    }
    __syncthreads();    // publishes P_s + es_red
    if (t < 16) {
        float s = 0.f;
#pragma unroll
        for (int ww = 0; ww < 8; ++ww) s += es_red[ww][t];
        inv_s[t] = 1.f / s;
    }

    // ---- Phase B: PV; wave w owns d-cols [32w, 32w+32) ----
    f32x4 acc2[2];
#pragma unroll
    for (int i = 0; i < 2; ++i) acc2[i] = (f32x4){0.f, 0.f, 0.f, 0.f};

#pragma unroll
    for (int ki = 0; ki < 32; ++ki) {
        bf16x8 pf = *(const bf16x8*)(
            P_s + lr * 1024 + ((32 * ki + 8 * lc) ^ ((lr & 7) << 3)));
        const size_t tbase =
            ((size_t)((b * 32 + ki) * 16 + 2 * w) << 9) + l * 8;
#pragma unroll
        for (int dbi = 0; dbi < 2; ++dbi) {
            bf16x8 vf = *(const bf16x8*)(VB + tbase + ((size_t)dbi << 9));
            acc2[dbi] = __builtin_amdgcn_mfma_f32_16x16x32_bf16(pf, vf, acc2[dbi], 0, 0, 0);
        }
    }
    __syncthreads();    // all P_s reads done; inv_s visible

    // normalize + write att (bf16) to padded LDS [16][264]
#pragma unroll
    for (int dbi = 0; dbi < 2; ++dbi)
#pragma unroll
        for (int r = 0; r < 4; ++r) {
            const int qi = lc * 4 + r;
            att_s[qi * 264 + 32 * w + 16 * dbi + lr] =
                f2bf(acc2[dbi][r] * inv_s[qi]);
        }
    __syncthreads();

    // ---- Phase C: out-proj; wave w owns out-cols [32w, 32w+32) ----
    bf16x8 af[8];
#pragma unroll
    for (int db = 0; db < 8; ++db)
        af[db] = *(const bf16x8*)(att_s + lr * 264 + db * 32 + 8 * lc);

#pragma unroll
    for (int cb = 0; cb < 2; ++cb) {
        const int jb = 32 * w + 16 * cb;
        f32x4 acc = {0.f, 0.f, 0.f, 0.f};
#pragma unroll
        for (int db = 0; db < 8; ++db) {
            bf16x8 bf = *(const bf16x8*)(Wob + (size_t)(jb + lr) * DD + db * 32 + 8 * lc);
            acc = __builtin_amdgcn_mfma_f32_16x16x32_bf16(af[db], bf, acc, 0, 0, 0);
        }
        const float bov = bo[jb + lr];
#pragma unroll
        for (int r = 0; r < 4; ++r)
            out[(size_t)(rowbase + lc * 4 + r) * DD + jb + lr] = acc[r] + bov;
    }
}

// ---------------------------------------------------------------------------
extern "C" void kernel_launch(void* const* d_in, const int* in_sizes, int n_in,
                              void* d_out, int out_size, void* d_ws, size_t ws_size,
                              hipStream_t stream) {
    const float* x  = (const float*)d_in[0];
    const float* Wq = (const float*)d_in[1];
    const float* bq = (const float*)d_in[2];
    const float* Wk = (const float*)d_in[3];
    const float* bk = (const float*)d_in[4];
    const float* Wv = (const float*)d_in[5];
    const float* bv = (const float*)d_in[6];
    const float* Wo = (const float*)d_in[7];
    const float* bo = (const float*)d_in[8];
    float* out = (float*)d_out;

    // ws layout (bf16): Qb | Kb | VB | xb | Wqb | Wkb | Wvb | Wob || qq | kk
    const size_t rows = (size_t)BB * SS;            // 2048
    unsigned short* Qb  = (unsigned short*)d_ws;
    unsigned short* Kb  = Qb + rows * DD;
    unsigned short* VB  = Kb + rows * DD;
    unsigned short* xb  = VB + rows * DD;
    unsigned short* Wqb = xb + rows * DD;
    unsigned short* Wkb = Wqb + (size_t)DD * DD;
    unsigned short* Wvb = Wkb + (size_t)DD * DD;
    unsigned short* Wob = Wvb + (size_t)DD * DD;
    float* qq    = (float*)(Wob + (size_t)DD * DD);
    float* kk    = qq + rows;

    cvt_bf16<<<384, 256, 0, stream>>>(x, Wq, Wk, Wv, Wo,
                                      xb, Wqb, Wkb, Wvb, Wob);
    qkv_mfma<<<(int)(rows / 16) * 3, 256, 0, stream>>>(
        xb, Wqb, bq, Wkb, bk, Wvb, bv, Qb, Kb, VB, qq, kk);
    attn_out_mfma<<<(int)(rows / 16), 512, 0, stream>>>(
        Qb, Kb, VB, qq, kk, Wob, bo, out);
}